// Round 5
// baseline (209.658 us; speedup 1.0000x reference)
//
#include <hip/hip_runtime.h>
#include <hip/hip_bf16.h>

// B=2, M=2048, HID=1024, NH=16, D=64.  No softmax in the reference, so
//   out = ((h Wq^T)(h Wk^T)^T (h Wv^T)) Wo^T
// reassociates twice:  S_{b,h} = K_h^T V_h  (64x64), and
//   out_b = Q_b @ T_b   with  T_b[h*64+d, n] = sum_j S_{b,h}[d,j] Wo[n, h*64+j]
//
// Dtypes: inputs fp32, d_out fp32; internal bf16 with fp32 accumulate
// (round-3/4: absmax 4.0 vs threshold 11.68).
//
// Round-5 deltas: final GEMM split-K=2 with fp32 atomicAdd into d_out
// (was 256 blocks = 1/CU, zero latency hiding); prep zeroes d_out.
//
// Pipeline:
//   0. prep: h->hb (bf16), Wq|Wk|Wv->wcat (bf16); zero S and d_out
//   1. QKVb = hb @ wcat^T        (4096x3072 bf16)            [MFMA GEMM]
//   2. S[b,h] = K_h^T V_h        (32 x 64x64 fp32, atomic)   [VALU]
//   3. Tt[b][n,k] = (S_h Wo_h^T)^T  (2 x 1024x1024 bf16)     [VALU, fp32 in]
//   4. out += Q @ Tt_b^T  split-K=2  (fp32 atomicAdd d_out)  [MFMA GEMM]

typedef unsigned short u16;
typedef unsigned int u32;
typedef __attribute__((ext_vector_type(8))) short bf16x8;
typedef __attribute__((ext_vector_type(4))) float f32x4;

__device__ __forceinline__ void async_copy16(void* lds, const void* g) {
  __builtin_amdgcn_global_load_lds((const __attribute__((address_space(1))) void*)g,
                                   (__attribute__((address_space(3))) void*)lds,
                                   16, 0, 0);
}

__device__ __forceinline__ u16 f2bf(float f) {
  union { __hip_bfloat16 h; u16 u; } c;
  c.h = __float2bfloat16(f);
  return c.u;
}
__device__ __forceinline__ float bflo(u32 w) {
  union { u32 u; float f; } c; c.u = w << 16; return c.f;
}
__device__ __forceinline__ float bfhi(u32 w) {
  union { u32 u; float f; } c; c.u = w & 0xFFFF0000u; return c.f;
}
__device__ __forceinline__ ushort4 cvt4(float4 v) {
  ushort4 o; o.x = f2bf(v.x); o.y = f2bf(v.y); o.z = f2bf(v.z); o.w = f2bf(v.w);
  return o;
}

// ---------------------------------------------------------------- prep ------
// h->hb, Wq|Wk|Wv->wcat (bf16); zero S and d_out.  Region bounds are
// multiples of 256 float4s -> block-uniform branches.
__global__ __launch_bounds__(256) void prep(const float4* __restrict__ h,
                                            const float4* __restrict__ wq,
                                            const float4* __restrict__ wk,
                                            const float4* __restrict__ wv,
                                            ushort4* __restrict__ hb,
                                            ushort4* __restrict__ wcat,
                                            float4* __restrict__ S,
                                            float4* __restrict__ outz) {
  int i = blockIdx.x * 256 + threadIdx.x;  // float4 units
  if (i < 1048576) { hb[i] = cvt4(h[i]); return; }          // h: 4096x1024
  i -= 1048576;
  if (i < 262144) { wcat[i] = cvt4(wq[i]); return; }
  i -= 262144;
  if (i < 262144) { wcat[262144 + i] = cvt4(wk[i]); return; }
  i -= 262144;
  if (i < 262144) { wcat[524288 + i] = cvt4(wv[i]); return; }
  i -= 262144;
  if (i < 8192) { S[i] = float4{0.f, 0.f, 0.f, 0.f}; return; }  // 32*64*64 fp32
  i -= 8192;
  outz[i] = float4{0.f, 0.f, 0.f, 0.f};                     // d_out: 4096x1024
}

// ------------------------------------------------------------- NT GEMM ------
// C[m,n] = sum_k A[m*lda+k] * B[n*K+k].  A,B bf16.  128x128 tile, BK=32,
// 4 waves (2x2), each wave 64x64 via 4x4 of 16x16x32 MFMA.
// blockIdx.z picks a K-split slab of length ksplit (atomicAdd epilogue when
// ATOMIC_OUT).  If B1 != nullptr, row-blocks with m0 >= 2048 use B1.
template <bool BF16_OUT, bool ATOMIC_OUT>
__global__ __launch_bounds__(256) void gemm_bt(const u16* __restrict__ A, int lda,
                                               const u16* __restrict__ B0,
                                               const u16* __restrict__ B1,
                                               void* __restrict__ Cv,
                                               int N, int K, int ksplit) {
  __shared__ u16 Als[128 * 32];
  __shared__ u16 Bls[128 * 32];
  const int t = threadIdx.x;
  const int lane = t & 63;
  const int wave = t >> 6;
  const int wm = (wave >> 1) * 64;
  const int wn = (wave & 1) * 64;
  const int lrow = lane & 15;      // MFMA m/n index
  const int lk = (lane >> 4) * 8;  // MFMA k offset (quad*8)
  const int m0 = blockIdx.y * 128;
  const int n0 = blockIdx.x * 128;
  const int kbeg = blockIdx.z * ksplit;
  const int kend = kbeg + ksplit;
  const u16* B = (B1 != nullptr && m0 >= 2048) ? B1 : B0;

  // staging: LDS tile row-major [128][32] bf16; thread t covers 16 B at t*16
  // (wave-uniform base + lane*16 -> legal global_load_lds dest).
  const int srow = t >> 2;
  const int scol = (t & 3) * 8;
  const u16* Ag0 = A + (size_t)(m0 + srow) * lda + scol;
  const u16* Bg0 = B + (size_t)(n0 + srow) * K + scol;
  u16* Al0 = Als + t * 8;
  u16* Bl0 = Bls + t * 8;

  f32x4 acc[4][4];
#pragma unroll
  for (int i = 0; i < 4; ++i)
#pragma unroll
    for (int j = 0; j < 4; ++j) acc[i][j] = {0.f, 0.f, 0.f, 0.f};

  for (int k0 = kbeg; k0 < kend; k0 += 32) {
    async_copy16(Al0,        Ag0 + k0);
    async_copy16(Al0 + 2048, Ag0 + (size_t)64 * lda + k0);
    async_copy16(Bl0,        Bg0 + k0);
    async_copy16(Bl0 + 2048, Bg0 + (size_t)64 * K + k0);
    __syncthreads();

    bf16x8 af[4], bfv[4];
#pragma unroll
    for (int i = 0; i < 4; ++i) {
      af[i]  = *(const bf16x8*)(Als + (wm + i * 16 + lrow) * 32 + lk);
      bfv[i] = *(const bf16x8*)(Bls + (wn + i * 16 + lrow) * 32 + lk);
    }
#pragma unroll
    for (int mi = 0; mi < 4; ++mi)
#pragma unroll
      for (int ni = 0; ni < 4; ++ni)
        acc[mi][ni] = __builtin_amdgcn_mfma_f32_16x16x32_bf16(
            af[mi], bfv[ni], acc[mi][ni], 0, 0, 0);
    __syncthreads();
  }

  // C/D layout (verified m89/m91): col = lane&15, row = (lane>>4)*4 + r
  const int crow0 = m0 + wm + (lane >> 4) * 4;
  const int ccol0 = n0 + wn + (lane & 15);
#pragma unroll
  for (int mi = 0; mi < 4; ++mi)
#pragma unroll
    for (int ni = 0; ni < 4; ++ni) {
      const int col = ccol0 + ni * 16;
#pragma unroll
      for (int r = 0; r < 4; ++r) {
        const size_t idx = (size_t)(crow0 + mi * 16 + r) * N + col;
        if (ATOMIC_OUT)      atomicAdd((float*)Cv + idx, acc[mi][ni][r]);
        else if (BF16_OUT)   ((u16*)Cv)[idx]   = f2bf(acc[mi][ni][r]);
        else                 ((float*)Cv)[idx] = acc[mi][ni][r];
      }
    }
}

// ------------------------------------------------------- S = K^T V ----------
// QKVb: (4096, 3072) bf16; cols [0,1024)=Q [1024,2048)=K [2048,3072)=V.
// grid (32 bh, 16 chunks of 128 rows); 32-row LDS stages, uint4 loads;
// atomicAdd into S (32 x 64 x 64 fp32).
__global__ __launch_bounds__(256) void s_kernel(const u16* __restrict__ QKV,
                                                float* __restrict__ S) {
  const int bh = blockIdx.x;
  const int b = bh >> 4, hh = bh & 15;
  const int row0 = b * 2048 + blockIdx.y * 128;
  const u16* Kg = QKV + (size_t)row0 * 3072 + 1024 + hh * 64;

  __shared__ float Ks[32][64];
  __shared__ float Vs[32][64];
  const int t = threadIdx.x;
  const int lr = t >> 3;        // 0..31
  const int lc = (t & 7) * 8;   // 0..56
  const int d1 = (t >> 4) * 4;
  const int d2 = (t & 15) * 4;

  float acc[4][4] = {};

  for (int r0 = 0; r0 < 128; r0 += 32) {
    const u16* kp = Kg + (size_t)(r0 + lr) * 3072 + lc;
    const uint4 kw = *(const uint4*)kp;
    const uint4 vw = *(const uint4*)(kp + 1024);  // V = K + 1024 cols
    __syncthreads();  // prev-iter readers done
    float* kd = &Ks[lr][lc];
    *(float4*)(kd)     = float4{bflo(kw.x), bfhi(kw.x), bflo(kw.y), bfhi(kw.y)};
    *(float4*)(kd + 4) = float4{bflo(kw.z), bfhi(kw.z), bflo(kw.w), bfhi(kw.w)};
    float* vd = &Vs[lr][lc];
    *(float4*)(vd)     = float4{bflo(vw.x), bfhi(vw.x), bflo(vw.y), bfhi(vw.y)};
    *(float4*)(vd + 4) = float4{bflo(vw.z), bfhi(vw.z), bflo(vw.w), bfhi(vw.w)};
    __syncthreads();
#pragma unroll
    for (int r = 0; r < 32; ++r) {
      float kv[4], vv[4];
      *(float4*)kv = *(const float4*)&Ks[r][d1];
      *(float4*)vv = *(const float4*)&Vs[r][d2];
#pragma unroll
      for (int i = 0; i < 4; ++i)
#pragma unroll
        for (int j = 0; j < 4; ++j) acc[i][j] += kv[i] * vv[j];
    }
  }
  float* Sp = S + (size_t)bh * 4096;
#pragma unroll
  for (int i = 0; i < 4; ++i)
#pragma unroll
    for (int j = 0; j < 4; ++j)
      atomicAdd(&Sp[(d1 + i) * 64 + d2 + j], acc[i][j]);
}

// ------------------------------------------- Tt = (S_h Wo_h^T)^T ------------
// T_b[h*64+d, n] = sum_j S_{b,h}[d,j] * Wo[n, h*64+j];  stored transposed
// (row n, col h*64+d) bf16 so the final GEMM can consume it NT-style.
// grid (8 n-chunks, 16 heads, 2 batches); S and Wo read as fp32.
__global__ __launch_bounds__(256) void t_kernel(const float* __restrict__ S,
                                                const float* __restrict__ Wo,
                                                u16* __restrict__ Tt) {
  const int n0 = blockIdx.x * 128;
  const int hh = blockIdx.y;
  const int b  = blockIdx.z;
  __shared__ float Ss[64][68];
  __shared__ float Ws[128][68];
  const int t = threadIdx.x;
  {
    const float* sg = S + (size_t)(b * 16 + hh) * 4096 + (t >> 2) * 64 + (t & 3) * 16;
    float* sd = &Ss[t >> 2][(t & 3) * 16];
#pragma unroll
    for (int i = 0; i < 4; ++i) *(float4*)(sd + 4 * i) = *(const float4*)(sg + 4 * i);
    const float* wg = Wo + (size_t)(n0 + (t >> 1)) * 1024 + hh * 64 + (t & 1) * 32;
    float* wd = &Ws[t >> 1][(t & 1) * 32];
#pragma unroll
    for (int i = 0; i < 8; ++i) *(float4*)(wd + 4 * i) = *(const float4*)(wg + 4 * i);
  }
  __syncthreads();

  const int td = (t >> 4) * 4;  // d = td..td+3
  const int tn = t & 15;        // n = n0 + tn + 16k
  float acc[4][8] = {};
  for (int jj = 0; jj < 64; jj += 4) {
    float4 sv[4], wv[8];
#pragma unroll
    for (int i = 0; i < 4; ++i) sv[i] = *(const float4*)&Ss[td + i][jj];
#pragma unroll
    for (int k = 0; k < 8; ++k) wv[k] = *(const float4*)&Ws[tn + 16 * k][jj];
#pragma unroll
    for (int i = 0; i < 4; ++i)
#pragma unroll
      for (int k = 0; k < 8; ++k)
        acc[i][k] += sv[i].x * wv[k].x + sv[i].y * wv[k].y +
                     sv[i].z * wv[k].z + sv[i].w * wv[k].w;
  }

  u16* tp = Tt + (size_t)b * 1048576;
#pragma unroll
  for (int k = 0; k < 8; ++k) {
    const int n = n0 + tn + 16 * k;
    ushort4 o;
    o.x = f2bf(acc[0][k]); o.y = f2bf(acc[1][k]);
    o.z = f2bf(acc[2][k]); o.w = f2bf(acc[3][k]);
    *(ushort4*)&tp[(size_t)n * 1024 + hh * 64 + td] = o;
  }
}

// ---------------------------------------------------------------------------
extern "C" void kernel_launch(void* const* d_in, const int* in_sizes, int n_in,
                              void* d_out, int out_size, void* d_ws, size_t ws_size,
                              hipStream_t stream) {
  const float* h  = (const float*)d_in[0];  // (4096, 1024) fp32
  // d_in[1] = key_pe: dead branch in reference, unused.
  const float* Wq = (const float*)d_in[2];
  const float* Wk = (const float*)d_in[3];
  const float* Wv = (const float*)d_in[4];
  const float* Wo = (const float*)d_in[5];

  char* ws = (char*)d_ws;
  u16*   hb   = (u16*)(ws);                    // 4096*1024*2 = 8 MiB @ 0
  u16*   wcat = (u16*)(ws + (8ull  << 20));    // 3072*1024*2 = 6 MiB
  u16*   QKVb = (u16*)(ws + (16ull << 20));    // 4096*3072*2 = 24 MiB
  float* S    = (float*)(ws + (40ull << 20));  // 32*64*64*4  = 0.5 MiB
  u16*   Tt   = (u16*)(ws + (41ull << 20));    // 2*1024*1024*2 = 4 MiB
  // total ws use: 45 MiB (ws_size = 256 MiB per round-3 fill WRITE_SIZE)

  // regions: h 1048576 | wq/wk/wv 3*262144 | S 8192 | d_out 1048576 float4s
  prep<<<11296, 256, 0, stream>>>((const float4*)h, (const float4*)Wq,
                                  (const float4*)Wk, (const float4*)Wv,
                                  (ushort4*)hb, (ushort4*)wcat, (float4*)S,
                                  (float4*)d_out);
  gemm_bt<true, false><<<dim3(24, 32, 1), 256, 0, stream>>>(
      hb, 1024, wcat, nullptr, QKVb, 3072, 1024, 1024);
  s_kernel<<<dim3(32, 16), 256, 0, stream>>>(QKVb, S);
  t_kernel<<<dim3(8, 16, 2), 256, 0, stream>>>(S, Wo, Tt);
  gemm_bt<false, true><<<dim3(8, 32, 2), 256, 0, stream>>>(
      QKVb, 3072, Tt, Tt + 1048576, d_out, 1024, 1024, 512);
}

// Round 6
// 184.992 us; speedup vs baseline: 1.1333x; 1.1333x over previous
//
#include <hip/hip_runtime.h>
#include <hip/hip_bf16.h>

// B=2, M=2048, HID=1024, NH=16, D=64.  No softmax in the reference, so
//   out = ((h Wq^T)(h Wk^T)^T (h Wv^T)) Wo^T
// reassociates twice:  S_{b,h} = K_h^T V_h  (64x64), and
//   out_b = Q_b @ T_b   with  T_b[h*64+d, n] = sum_j S_{b,h}[d,j] Wo[n, h*64+j]
//
// Dtypes: inputs fp32, d_out fp32; internal bf16 with fp32 accumulate
// (rounds 3-5: absmax 4.0 vs threshold 11.68).
//
// Round-6 deltas: (a) revert round-5 split-K atomic epilogue (regressed +15us:
// 67 MB atomic RMW + 16 MiB extra zero-fill); (b) GEMM K-loop BK=32 -> 64
// (half the barrier drains; LDS 32 KB keeps >=3 blocks/CU); (c) XOR-swizzled
// LDS tile (group ^= row&7, applied on the global-read side so the
// global_load_lds dest stays wave-uniform base + lane*16) -> fragment
// ds_read_b128 goes 8-way-conflict -> conflict-free (SQ_LDS_BANK_CONFLICT
// was 3.1M cycles on gemm1).
//
// Pipeline:
//   0. prep: h->hb (bf16), Wq|Wk|Wv->wcat (bf16); zero S
//   1. QKVb = hb @ wcat^T        (4096x3072 bf16)            [MFMA GEMM]
//   2. S[b,h] = K_h^T V_h        (32 x 64x64 fp32, atomic)   [VALU]
//   3. Tt[b][n,k] = (S_h Wo_h^T)^T  (2 x 1024x1024 bf16)     [VALU, fp32 in]
//   4. out = Q @ Tt_b^T          (4096x1024 fp32 -> d_out)   [MFMA GEMM]

typedef unsigned short u16;
typedef unsigned int u32;
typedef __attribute__((ext_vector_type(8))) short bf16x8;
typedef __attribute__((ext_vector_type(4))) float f32x4;

__device__ __forceinline__ void async_copy16(void* lds, const void* g) {
  __builtin_amdgcn_global_load_lds((const __attribute__((address_space(1))) void*)g,
                                   (__attribute__((address_space(3))) void*)lds,
                                   16, 0, 0);
}

__device__ __forceinline__ u16 f2bf(float f) {
  union { __hip_bfloat16 h; u16 u; } c;
  c.h = __float2bfloat16(f);
  return c.u;
}
__device__ __forceinline__ float bflo(u32 w) {
  union { u32 u; float f; } c; c.u = w << 16; return c.f;
}
__device__ __forceinline__ float bfhi(u32 w) {
  union { u32 u; float f; } c; c.u = w & 0xFFFF0000u; return c.f;
}
__device__ __forceinline__ ushort4 cvt4(float4 v) {
  ushort4 o; o.x = f2bf(v.x); o.y = f2bf(v.y); o.z = f2bf(v.z); o.w = f2bf(v.w);
  return o;
}

// ---------------------------------------------------------------- prep ------
// h->hb, Wq|Wk|Wv->wcat (bf16); zero S.  Region bounds are multiples of 256
// float4s -> block-uniform branches.
__global__ __launch_bounds__(256) void prep(const float4* __restrict__ h,
                                            const float4* __restrict__ wq,
                                            const float4* __restrict__ wk,
                                            const float4* __restrict__ wv,
                                            ushort4* __restrict__ hb,
                                            ushort4* __restrict__ wcat,
                                            float4* __restrict__ S) {
  int i = blockIdx.x * 256 + threadIdx.x;  // float4 units
  if (i < 1048576) { hb[i] = cvt4(h[i]); return; }          // h: 4096x1024
  i -= 1048576;
  if (i < 262144) { wcat[i] = cvt4(wq[i]); return; }
  i -= 262144;
  if (i < 262144) { wcat[262144 + i] = cvt4(wk[i]); return; }
  i -= 262144;
  if (i < 262144) { wcat[524288 + i] = cvt4(wv[i]); return; }
  i -= 262144;
  S[i] = float4{0.f, 0.f, 0.f, 0.f};                        // 32*64*64 fp32
}

// ------------------------------------------------------------- NT GEMM ------
// C[m,n] = sum_k A[m*lda+k] * B[n*K+k].  A,B bf16.  128x128 tile, BK=64,
// 4 waves (2x2), each wave 64x64 via 4x4 of 16x16x32 MFMA (2 k-halves).
// LDS tile [128][64] bf16 with XOR swizzle: LDS(row, g) holds global 16-B
// k-group g ^ (row&7).  Swizzle applied on the global-read side so the
// global_load_lds LDS dest is the plain wave-uniform base + lane*16.
// If B1 != nullptr, row-blocks with m0 >= 2048 use B1 (per-batch T).
template <bool BF16_OUT>
__global__ __launch_bounds__(256) void gemm_bt(const u16* __restrict__ A, int lda,
                                               const u16* __restrict__ B0,
                                               const u16* __restrict__ B1,
                                               void* __restrict__ Cv,
                                               int N, int K) {
  __shared__ u16 Als[128 * 64];
  __shared__ u16 Bls[128 * 64];
  const int t = threadIdx.x;
  const int lane = t & 63;
  const int wave = t >> 6;
  const int wm = (wave >> 1) * 64;
  const int wn = (wave & 1) * 64;
  const int lrow = lane & 15;      // MFMA m/n index
  const int quad = lane >> 4;      // MFMA k-group (16-B units)
  const int m0 = blockIdx.y * 128;
  const int n0 = blockIdx.x * 128;
  const u16* B = (B1 != nullptr && m0 >= 2048) ? B1 : B0;

  // staging: copy c covers rows c*32..c*32+31; thread t -> row c*32+(t>>3),
  // LDS group t&7 which holds global group (t&7)^((t>>3)&7).
  const int srow = t >> 3;
  const int scol = (((t & 7) ^ (srow & 7)) * 8);
  const u16* Ag0 = A + (size_t)(m0 + srow) * lda + scol;
  const u16* Bg0 = B + (size_t)(n0 + srow) * K + scol;
  u16* Al0 = Als + t * 8;  // + c*2048 u16 per copy (32 rows)
  u16* Bl0 = Bls + t * 8;

  f32x4 acc[4][4];
#pragma unroll
  for (int i = 0; i < 4; ++i)
#pragma unroll
    for (int j = 0; j < 4; ++j) acc[i][j] = {0.f, 0.f, 0.f, 0.f};

  for (int k0 = 0; k0 < K; k0 += 64) {
#pragma unroll
    for (int c = 0; c < 4; ++c)
      async_copy16(Al0 + c * 2048, Ag0 + (size_t)(c * 32) * lda + k0);
#pragma unroll
    for (int c = 0; c < 4; ++c)
      async_copy16(Bl0 + c * 2048, Bg0 + (size_t)(c * 32) * K + k0);
    __syncthreads();

#pragma unroll
    for (int half = 0; half < 2; ++half) {
      const int gg = quad + half * 4;  // global k-group within BK=64
      bf16x8 af[4], bfv[4];
#pragma unroll
      for (int i = 0; i < 4; ++i) {
        const int ra = wm + i * 16 + lrow;
        const int rb = wn + i * 16 + lrow;
        af[i]  = *(const bf16x8*)(Als + ra * 64 + ((gg ^ (ra & 7)) << 3));
        bfv[i] = *(const bf16x8*)(Bls + rb * 64 + ((gg ^ (rb & 7)) << 3));
      }
#pragma unroll
      for (int mi = 0; mi < 4; ++mi)
#pragma unroll
        for (int ni = 0; ni < 4; ++ni)
          acc[mi][ni] = __builtin_amdgcn_mfma_f32_16x16x32_bf16(
              af[mi], bfv[ni], acc[mi][ni], 0, 0, 0);
    }
    __syncthreads();
  }

  // C/D layout (verified m89/m91): col = lane&15, row = (lane>>4)*4 + r
  const int crow0 = m0 + wm + (lane >> 4) * 4;
  const int ccol0 = n0 + wn + (lane & 15);
#pragma unroll
  for (int mi = 0; mi < 4; ++mi)
#pragma unroll
    for (int ni = 0; ni < 4; ++ni) {
      const int col = ccol0 + ni * 16;
#pragma unroll
      for (int r = 0; r < 4; ++r) {
        const size_t idx = (size_t)(crow0 + mi * 16 + r) * N + col;
        if (BF16_OUT) ((u16*)Cv)[idx]   = f2bf(acc[mi][ni][r]);
        else          ((float*)Cv)[idx] = acc[mi][ni][r];
      }
    }
}

// ------------------------------------------------------- S = K^T V ----------
// QKVb: (4096, 3072) bf16; cols [0,1024)=Q [1024,2048)=K [2048,3072)=V.
// grid (32 bh, 16 chunks of 128 rows); 32-row LDS stages, uint4 loads;
// atomicAdd into S (32 x 64 x 64 fp32).
__global__ __launch_bounds__(256) void s_kernel(const u16* __restrict__ QKV,
                                                float* __restrict__ S) {
  const int bh = blockIdx.x;
  const int b = bh >> 4, hh = bh & 15;
  const int row0 = b * 2048 + blockIdx.y * 128;
  const u16* Kg = QKV + (size_t)row0 * 3072 + 1024 + hh * 64;

  __shared__ float Ks[32][64];
  __shared__ float Vs[32][64];
  const int t = threadIdx.x;
  const int lr = t >> 3;        // 0..31
  const int lc = (t & 7) * 8;   // 0..56
  const int d1 = (t >> 4) * 4;
  const int d2 = (t & 15) * 4;

  float acc[4][4] = {};

  for (int r0 = 0; r0 < 128; r0 += 32) {
    const u16* kp = Kg + (size_t)(r0 + lr) * 3072 + lc;
    const uint4 kw = *(const uint4*)kp;
    const uint4 vw = *(const uint4*)(kp + 1024);  // V = K + 1024 cols
    __syncthreads();  // prev-iter readers done
    float* kd = &Ks[lr][lc];
    *(float4*)(kd)     = float4{bflo(kw.x), bfhi(kw.x), bflo(kw.y), bfhi(kw.y)};
    *(float4*)(kd + 4) = float4{bflo(kw.z), bfhi(kw.z), bflo(kw.w), bfhi(kw.w)};
    float* vd = &Vs[lr][lc];
    *(float4*)(vd)     = float4{bflo(vw.x), bfhi(vw.x), bflo(vw.y), bfhi(vw.y)};
    *(float4*)(vd + 4) = float4{bflo(vw.z), bfhi(vw.z), bflo(vw.w), bfhi(vw.w)};
    __syncthreads();
#pragma unroll
    for (int r = 0; r < 32; ++r) {
      float kv[4], vv[4];
      *(float4*)kv = *(const float4*)&Ks[r][d1];
      *(float4*)vv = *(const float4*)&Vs[r][d2];
#pragma unroll
      for (int i = 0; i < 4; ++i)
#pragma unroll
        for (int j = 0; j < 4; ++j) acc[i][j] += kv[i] * vv[j];
    }
  }
  float* Sp = S + (size_t)bh * 4096;
#pragma unroll
  for (int i = 0; i < 4; ++i)
#pragma unroll
    for (int j = 0; j < 4; ++j)
      atomicAdd(&Sp[(d1 + i) * 64 + d2 + j], acc[i][j]);
}

// ------------------------------------------- Tt = (S_h Wo_h^T)^T ------------
// T_b[h*64+d, n] = sum_j S_{b,h}[d,j] * Wo[n, h*64+j];  stored transposed
// (row n, col h*64+d) bf16 so the final GEMM can consume it NT-style.
// grid (8 n-chunks, 16 heads, 2 batches); S and Wo read as fp32.
__global__ __launch_bounds__(256) void t_kernel(const float* __restrict__ S,
                                                const float* __restrict__ Wo,
                                                u16* __restrict__ Tt) {
  const int n0 = blockIdx.x * 128;
  const int hh = blockIdx.y;
  const int b  = blockIdx.z;
  __shared__ float Ss[64][68];
  __shared__ float Ws[128][68];
  const int t = threadIdx.x;
  {
    const float* sg = S + (size_t)(b * 16 + hh) * 4096 + (t >> 2) * 64 + (t & 3) * 16;
    float* sd = &Ss[t >> 2][(t & 3) * 16];
#pragma unroll
    for (int i = 0; i < 4; ++i) *(float4*)(sd + 4 * i) = *(const float4*)(sg + 4 * i);
    const float* wg = Wo + (size_t)(n0 + (t >> 1)) * 1024 + hh * 64 + (t & 1) * 32;
    float* wd = &Ws[t >> 1][(t & 1) * 32];
#pragma unroll
    for (int i = 0; i < 8; ++i) *(float4*)(wd + 4 * i) = *(const float4*)(wg + 4 * i);
  }
  __syncthreads();

  const int td = (t >> 4) * 4;  // d = td..td+3
  const int tn = t & 15;        // n = n0 + tn + 16k
  float acc[4][8] = {};
  for (int jj = 0; jj < 64; jj += 4) {
    float4 sv[4], wv[8];
#pragma unroll
    for (int i = 0; i < 4; ++i) sv[i] = *(const float4*)&Ss[td + i][jj];
#pragma unroll
    for (int k = 0; k < 8; ++k) wv[k] = *(const float4*)&Ws[tn + 16 * k][jj];
#pragma unroll
    for (int i = 0; i < 4; ++i)
#pragma unroll
      for (int k = 0; k < 8; ++k)
        acc[i][k] += sv[i].x * wv[k].x + sv[i].y * wv[k].y +
                     sv[i].z * wv[k].z + sv[i].w * wv[k].w;
  }

  u16* tp = Tt + (size_t)b * 1048576;
#pragma unroll
  for (int k = 0; k < 8; ++k) {
    const int n = n0 + tn + 16 * k;
    ushort4 o;
    o.x = f2bf(acc[0][k]); o.y = f2bf(acc[1][k]);
    o.z = f2bf(acc[2][k]); o.w = f2bf(acc[3][k]);
    *(ushort4*)&tp[(size_t)n * 1024 + hh * 64 + td] = o;
  }
}

// ---------------------------------------------------------------------------
extern "C" void kernel_launch(void* const* d_in, const int* in_sizes, int n_in,
                              void* d_out, int out_size, void* d_ws, size_t ws_size,
                              hipStream_t stream) {
  const float* h  = (const float*)d_in[0];  // (4096, 1024) fp32
  // d_in[1] = key_pe: dead branch in reference, unused.
  const float* Wq = (const float*)d_in[2];
  const float* Wk = (const float*)d_in[3];
  const float* Wv = (const float*)d_in[4];
  const float* Wo = (const float*)d_in[5];

  char* ws = (char*)d_ws;
  u16*   hb   = (u16*)(ws);                    // 4096*1024*2 = 8 MiB @ 0
  u16*   wcat = (u16*)(ws + (8ull  << 20));    // 3072*1024*2 = 6 MiB
  u16*   QKVb = (u16*)(ws + (16ull << 20));    // 4096*3072*2 = 24 MiB
  float* S    = (float*)(ws + (40ull << 20));  // 32*64*64*4  = 0.5 MiB
  u16*   Tt   = (u16*)(ws + (41ull << 20));    // 2*1024*1024*2 = 4 MiB
  // total ws use: 45 MiB (ws_size = 256 MiB per round-3 fill WRITE_SIZE)

  prep<<<7200, 256, 0, stream>>>((const float4*)h, (const float4*)Wq,
                                 (const float4*)Wk, (const float4*)Wv,
                                 (ushort4*)hb, (ushort4*)wcat, (float4*)S);
  gemm_bt<true><<<dim3(24, 32), 256, 0, stream>>>(hb, 1024, wcat, nullptr,
                                                  QKVb, 3072, 1024);
  s_kernel<<<dim3(32, 16), 256, 0, stream>>>(QKVb, S);
  t_kernel<<<dim3(8, 16, 2), 256, 0, stream>>>(S, Wo, Tt);
  gemm_bt<false><<<dim3(8, 32), 256, 0, stream>>>(QKVb, 3072, Tt, Tt + 1048576,
                                                  d_out, 1024, 1024);
}

// Round 7
// 163.080 us; speedup vs baseline: 1.2856x; 1.1344x over previous
//
#include <hip/hip_runtime.h>
#include <hip/hip_bf16.h>

// B=2, M=2048, HID=1024, NH=16, D=64.  No softmax in the reference, so
//   out = ((h Wq^T)(h Wk^T)^T (h Wv^T)) Wo^T
// reassociates twice:  S_{b,h} = K_h^T V_h  (64x64), and
//   out_b = Q_b @ T_b   with  T_b[h*64+d, n] = sum_j S_{b,h}[d,j] Wo[n, h*64+j]
//
// Dtypes: inputs fp32, d_out fp32; internal bf16 with fp32 accumulate
// (rounds 3-6: absmax 4.0 vs threshold 11.68).
//
// Round-7 delta: s_kernel atomics -> non-atomic partials + reduce kernel.
// Round-6 profile: s_kernel 41.8us, WRITE_SIZE 32MB for a 0.5MB output =
// 2M device-scope atomicAdds RMW'ing at the memory side (per-XCD L2s are
// non-coherent, so device atomics can't stay in L2).  Lesson (also explains
// round-5 split-K regression): dense-reduction atomics cost ~10x their bytes.
//
// Pipeline:
//   0. prep: h->hb (bf16), Wq|Wk|Wv->wcat (bf16)
//   1. QKVb = hb @ wcat^T        (4096x3072 bf16)            [MFMA GEMM]
//   2. Spart[bh,c] = K^T V partial over 128 rows  (plain stores)  [VALU]
//   2b. S = sum_c Spart          (reduce, 8MB read)          [BW]
//   3. Tt[b][n,k] = (S_h Wo_h^T)^T  (2 x 1024x1024 bf16)     [VALU, fp32 in]
//   4. out = Q @ Tt_b^T          (4096x1024 fp32 -> d_out)   [MFMA GEMM]

typedef unsigned short u16;
typedef unsigned int u32;
typedef __attribute__((ext_vector_type(8))) short bf16x8;
typedef __attribute__((ext_vector_type(4))) float f32x4;

__device__ __forceinline__ void async_copy16(void* lds, const void* g) {
  __builtin_amdgcn_global_load_lds((const __attribute__((address_space(1))) void*)g,
                                   (__attribute__((address_space(3))) void*)lds,
                                   16, 0, 0);
}

__device__ __forceinline__ u16 f2bf(float f) {
  union { __hip_bfloat16 h; u16 u; } c;
  c.h = __float2bfloat16(f);
  return c.u;
}
__device__ __forceinline__ float bflo(u32 w) {
  union { u32 u; float f; } c; c.u = w << 16; return c.f;
}
__device__ __forceinline__ float bfhi(u32 w) {
  union { u32 u; float f; } c; c.u = w & 0xFFFF0000u; return c.f;
}
__device__ __forceinline__ ushort4 cvt4(float4 v) {
  ushort4 o; o.x = f2bf(v.x); o.y = f2bf(v.y); o.z = f2bf(v.z); o.w = f2bf(v.w);
  return o;
}

// ---------------------------------------------------------------- prep ------
// h->hb, Wq|Wk|Wv->wcat (bf16).  Region bounds are multiples of 256 float4s
// -> block-uniform branches.  (No S zeroing: s-path is non-atomic now.)
__global__ __launch_bounds__(256) void prep(const float4* __restrict__ h,
                                            const float4* __restrict__ wq,
                                            const float4* __restrict__ wk,
                                            const float4* __restrict__ wv,
                                            ushort4* __restrict__ hb,
                                            ushort4* __restrict__ wcat) {
  int i = blockIdx.x * 256 + threadIdx.x;  // float4 units
  if (i < 1048576) { hb[i] = cvt4(h[i]); return; }          // h: 4096x1024
  i -= 1048576;
  if (i < 262144) { wcat[i] = cvt4(wq[i]); return; }
  i -= 262144;
  if (i < 262144) { wcat[262144 + i] = cvt4(wk[i]); return; }
  i -= 262144;
  wcat[524288 + i] = cvt4(wv[i]);
}

// ------------------------------------------------------------- NT GEMM ------
// C[m,n] = sum_k A[m*lda+k] * B[n*K+k].  A,B bf16.  128x128 tile, BK=64,
// 4 waves (2x2), each wave 64x64 via 4x4 of 16x16x32 MFMA (2 k-halves).
// LDS tile [128][64] bf16 with XOR swizzle: LDS(row, g) holds global 16-B
// k-group g ^ (row&7); swizzle applied on the global-read side so the
// global_load_lds dest stays wave-uniform base + lane*16.
// If B1 != nullptr, row-blocks with m0 >= 2048 use B1 (per-batch T).
template <bool BF16_OUT>
__global__ __launch_bounds__(256) void gemm_bt(const u16* __restrict__ A, int lda,
                                               const u16* __restrict__ B0,
                                               const u16* __restrict__ B1,
                                               void* __restrict__ Cv,
                                               int N, int K) {
  __shared__ u16 Als[128 * 64];
  __shared__ u16 Bls[128 * 64];
  const int t = threadIdx.x;
  const int lane = t & 63;
  const int wave = t >> 6;
  const int wm = (wave >> 1) * 64;
  const int wn = (wave & 1) * 64;
  const int lrow = lane & 15;      // MFMA m/n index
  const int quad = lane >> 4;      // MFMA k-group (16-B units)
  const int m0 = blockIdx.y * 128;
  const int n0 = blockIdx.x * 128;
  const u16* B = (B1 != nullptr && m0 >= 2048) ? B1 : B0;

  // staging: copy c covers rows c*32..c*32+31; thread t -> row c*32+(t>>3),
  // LDS group t&7 which holds global group (t&7)^((t>>3)&7).
  const int srow = t >> 3;
  const int scol = (((t & 7) ^ (srow & 7)) * 8);
  const u16* Ag0 = A + (size_t)(m0 + srow) * lda + scol;
  const u16* Bg0 = B + (size_t)(n0 + srow) * K + scol;
  u16* Al0 = Als + t * 8;  // + c*2048 u16 per copy (32 rows)
  u16* Bl0 = Bls + t * 8;

  f32x4 acc[4][4];
#pragma unroll
  for (int i = 0; i < 4; ++i)
#pragma unroll
    for (int j = 0; j < 4; ++j) acc[i][j] = {0.f, 0.f, 0.f, 0.f};

  for (int k0 = 0; k0 < K; k0 += 64) {
#pragma unroll
    for (int c = 0; c < 4; ++c)
      async_copy16(Al0 + c * 2048, Ag0 + (size_t)(c * 32) * lda + k0);
#pragma unroll
    for (int c = 0; c < 4; ++c)
      async_copy16(Bl0 + c * 2048, Bg0 + (size_t)(c * 32) * K + k0);
    __syncthreads();

#pragma unroll
    for (int half = 0; half < 2; ++half) {
      const int gg = quad + half * 4;  // global k-group within BK=64
      bf16x8 af[4], bfv[4];
#pragma unroll
      for (int i = 0; i < 4; ++i) {
        const int ra = wm + i * 16 + lrow;
        const int rb = wn + i * 16 + lrow;
        af[i]  = *(const bf16x8*)(Als + ra * 64 + ((gg ^ (ra & 7)) << 3));
        bfv[i] = *(const bf16x8*)(Bls + rb * 64 + ((gg ^ (rb & 7)) << 3));
      }
#pragma unroll
      for (int mi = 0; mi < 4; ++mi)
#pragma unroll
        for (int ni = 0; ni < 4; ++ni)
          acc[mi][ni] = __builtin_amdgcn_mfma_f32_16x16x32_bf16(
              af[mi], bfv[ni], acc[mi][ni], 0, 0, 0);
    }
    __syncthreads();
  }

  // C/D layout (verified m89/m91): col = lane&15, row = (lane>>4)*4 + r
  const int crow0 = m0 + wm + (lane >> 4) * 4;
  const int ccol0 = n0 + wn + (lane & 15);
#pragma unroll
  for (int mi = 0; mi < 4; ++mi)
#pragma unroll
    for (int ni = 0; ni < 4; ++ni) {
      const int col = ccol0 + ni * 16;
#pragma unroll
      for (int r = 0; r < 4; ++r) {
        const size_t idx = (size_t)(crow0 + mi * 16 + r) * N + col;
        if (BF16_OUT) ((u16*)Cv)[idx]   = f2bf(acc[mi][ni][r]);
        else          ((float*)Cv)[idx] = acc[mi][ni][r];
      }
    }
}

// --------------------------------------------- Spart = partial K^T V --------
// QKVb: (4096, 3072) bf16; cols [0,1024)=Q [1024,2048)=K [2048,3072)=V.
// grid (32 bh, 16 chunks of 128 rows); 64-row LDS stages; each block writes
// its private 64x64 partial to Spart[bh*16 + chunk] with plain stores.
__global__ __launch_bounds__(256) void s_kernel(const u16* __restrict__ QKV,
                                                float* __restrict__ Spart) {
  const int bh = blockIdx.x;
  const int b = bh >> 4, hh = bh & 15;
  const int row0 = b * 2048 + blockIdx.y * 128;
  const u16* Kg = QKV + (size_t)row0 * 3072 + 1024 + hh * 64;

  __shared__ float Ks[64][64];
  __shared__ float Vs[64][64];
  const int t = threadIdx.x;
  const int lr = t >> 2;        // 0..63 row within stage
  const int lc = (t & 3) * 16;  // col group (16 cols)
  const int d1 = (t >> 4) * 4;
  const int d2 = (t & 15) * 4;

  float acc[4][4] = {};

  for (int r0 = 0; r0 < 128; r0 += 64) {
    const u16* kp = Kg + (size_t)(r0 + lr) * 3072 + lc;
    const uint4 kw0 = *(const uint4*)kp;
    const uint4 kw1 = *(const uint4*)(kp + 8);
    const uint4 vw0 = *(const uint4*)(kp + 1024);  // V = K + 1024 cols
    const uint4 vw1 = *(const uint4*)(kp + 1032);
    __syncthreads();  // prev-iter readers done
    float* kd = &Ks[lr][lc];
    *(float4*)(kd)      = float4{bflo(kw0.x), bfhi(kw0.x), bflo(kw0.y), bfhi(kw0.y)};
    *(float4*)(kd + 4)  = float4{bflo(kw0.z), bfhi(kw0.z), bflo(kw0.w), bfhi(kw0.w)};
    *(float4*)(kd + 8)  = float4{bflo(kw1.x), bfhi(kw1.x), bflo(kw1.y), bfhi(kw1.y)};
    *(float4*)(kd + 12) = float4{bflo(kw1.z), bfhi(kw1.z), bflo(kw1.w), bfhi(kw1.w)};
    float* vd = &Vs[lr][lc];
    *(float4*)(vd)      = float4{bflo(vw0.x), bfhi(vw0.x), bflo(vw0.y), bfhi(vw0.y)};
    *(float4*)(vd + 4)  = float4{bflo(vw0.z), bfhi(vw0.z), bflo(vw0.w), bfhi(vw0.w)};
    *(float4*)(vd + 8)  = float4{bflo(vw1.x), bfhi(vw1.x), bflo(vw1.y), bfhi(vw1.y)};
    *(float4*)(vd + 12) = float4{bflo(vw1.z), bfhi(vw1.z), bflo(vw1.w), bfhi(vw1.w)};
    __syncthreads();
#pragma unroll
    for (int r = 0; r < 64; ++r) {
      float kv[4], vv[4];
      *(float4*)kv = *(const float4*)&Ks[r][d1];
      *(float4*)vv = *(const float4*)&Vs[r][d2];
#pragma unroll
      for (int i = 0; i < 4; ++i)
#pragma unroll
        for (int j = 0; j < 4; ++j) acc[i][j] += kv[i] * vv[j];
    }
  }
  float* Sp = Spart + ((size_t)bh * 16 + blockIdx.y) * 4096;
#pragma unroll
  for (int i = 0; i < 4; ++i)
    *(float4*)&Sp[(d1 + i) * 64 + d2] =
        float4{acc[i][0], acc[i][1], acc[i][2], acc[i][3]};
}

// ---------------------------------------------------- S = sum_c Spart -------
// 32 bh x 1024 float4 outputs; each thread sums 16 chunk partials.
__global__ __launch_bounds__(256) void reduce_s(const float4* __restrict__ Spart,
                                                float4* __restrict__ S) {
  const int g = blockIdx.x * 256 + threadIdx.x;  // 0..32767
  const int bh = g >> 10, j = g & 1023;
  const float4* p = Spart + (size_t)bh * 16384 + j;  // 16 chunks * 1024 f4
  float4 a = {0.f, 0.f, 0.f, 0.f};
#pragma unroll
  for (int c = 0; c < 16; ++c) {
    const float4 v = p[(size_t)c * 1024];
    a.x += v.x; a.y += v.y; a.z += v.z; a.w += v.w;
  }
  S[g] = a;
}

// ------------------------------------------- Tt = (S_h Wo_h^T)^T ------------
// T_b[h*64+d, n] = sum_j S_{b,h}[d,j] * Wo[n, h*64+j];  stored transposed
// (row n, col h*64+d) bf16 so the final GEMM can consume it NT-style.
// grid (8 n-chunks, 16 heads, 2 batches); S and Wo read as fp32.
__global__ __launch_bounds__(256) void t_kernel(const float* __restrict__ S,
                                                const float* __restrict__ Wo,
                                                u16* __restrict__ Tt) {
  const int n0 = blockIdx.x * 128;
  const int hh = blockIdx.y;
  const int b  = blockIdx.z;
  __shared__ float Ss[64][68];
  __shared__ float Ws[128][68];
  const int t = threadIdx.x;
  {
    const float* sg = S + (size_t)(b * 16 + hh) * 4096 + (t >> 2) * 64 + (t & 3) * 16;
    float* sd = &Ss[t >> 2][(t & 3) * 16];
#pragma unroll
    for (int i = 0; i < 4; ++i) *(float4*)(sd + 4 * i) = *(const float4*)(sg + 4 * i);
    const float* wg = Wo + (size_t)(n0 + (t >> 1)) * 1024 + hh * 64 + (t & 1) * 32;
    float* wd = &Ws[t >> 1][(t & 1) * 32];
#pragma unroll
    for (int i = 0; i < 8; ++i) *(float4*)(wd + 4 * i) = *(const float4*)(wg + 4 * i);
  }
  __syncthreads();

  const int td = (t >> 4) * 4;  // d = td..td+3
  const int tn = t & 15;        // n = n0 + tn + 16k
  float acc[4][8] = {};
  for (int jj = 0; jj < 64; jj += 4) {
    float4 sv[4], wv[8];
#pragma unroll
    for (int i = 0; i < 4; ++i) sv[i] = *(const float4*)&Ss[td + i][jj];
#pragma unroll
    for (int k = 0; k < 8; ++k) wv[k] = *(const float4*)&Ws[tn + 16 * k][jj];
#pragma unroll
    for (int i = 0; i < 4; ++i)
#pragma unroll
      for (int k = 0; k < 8; ++k)
        acc[i][k] += sv[i].x * wv[k].x + sv[i].y * wv[k].y +
                     sv[i].z * wv[k].z + sv[i].w * wv[k].w;
  }

  u16* tp = Tt + (size_t)b * 1048576;
#pragma unroll
  for (int k = 0; k < 8; ++k) {
    const int n = n0 + tn + 16 * k;
    ushort4 o;
    o.x = f2bf(acc[0][k]); o.y = f2bf(acc[1][k]);
    o.z = f2bf(acc[2][k]); o.w = f2bf(acc[3][k]);
    *(ushort4*)&tp[(size_t)n * 1024 + hh * 64 + td] = o;
  }
}

// ---------------------------------------------------------------------------
extern "C" void kernel_launch(void* const* d_in, const int* in_sizes, int n_in,
                              void* d_out, int out_size, void* d_ws, size_t ws_size,
                              hipStream_t stream) {
  const float* h  = (const float*)d_in[0];  // (4096, 1024) fp32
  // d_in[1] = key_pe: dead branch in reference, unused.
  const float* Wq = (const float*)d_in[2];
  const float* Wk = (const float*)d_in[3];
  const float* Wv = (const float*)d_in[4];
  const float* Wo = (const float*)d_in[5];

  char* ws = (char*)d_ws;
  u16*   hb    = (u16*)(ws);                    // 4096*1024*2 = 8 MiB @ 0
  u16*   wcat  = (u16*)(ws + (8ull  << 20));    // 3072*1024*2 = 6 MiB
  u16*   QKVb  = (u16*)(ws + (16ull << 20));    // 4096*3072*2 = 24 MiB
  float* S     = (float*)(ws + (40ull << 20));  // 32*64*64*4  = 0.5 MiB
  u16*   Tt    = (u16*)(ws + (41ull << 20));    // 2*1024*1024*2 = 4 MiB
  float* Spart = (float*)(ws + (48ull << 20));  // 512*64*64*4 = 8 MiB
  // total ws use: 56 MiB (ws_size = 256 MiB per round-3 fill WRITE_SIZE)

  prep<<<7168, 256, 0, stream>>>((const float4*)h, (const float4*)Wq,
                                 (const float4*)Wk, (const float4*)Wv,
                                 (ushort4*)hb, (ushort4*)wcat);
  gemm_bt<true><<<dim3(24, 32), 256, 0, stream>>>(hb, 1024, wcat, nullptr,
                                                  QKVb, 3072, 1024);
  s_kernel<<<dim3(32, 16), 256, 0, stream>>>(QKVb, Spart);
  reduce_s<<<128, 256, 0, stream>>>((const float4*)Spart, (float4*)S);
  t_kernel<<<dim3(8, 16, 2), 256, 0, stream>>>(S, Wo, Tt);
  gemm_bt<false><<<dim3(8, 32), 256, 0, stream>>>(QKVb, 3072, Tt, Tt + 1048576,
                                                  d_out, 1024, 1024);
}